// Round 7
// baseline (367.165 us; speedup 1.0000x reference)
//
#include <hip/hip_runtime.h>
#include <hip/hip_fp16.h>
#include <math.h>

// Problem constants
#define B_     4
#define CIN    128
#define LEN    2048
#define DMODEL 256
#define DSTATE 16
#define NHEADS 256
#define DINNER 768
#define CONVDIM 800      // DINNER + 2*DSTATE
#define DINPROJ 1824     // 2*DINNER + 2*DSTATE + NHEADS
#define EPS_   1e-5f
#define CHUNK  64
#define NCHUNK 32        // LEN / CHUNK

typedef _Float16 f16x8 __attribute__((ext_vector_type(8)));
typedef float    f32x4 __attribute__((ext_vector_type(4)));

__device__ __forceinline__ float silu_(float x){ return x / (1.0f + __expf(-x)); }
__device__ __forceinline__ float softplus_(float x){
    return x > 0.f ? x + log1pf(__expf(-x)) : log1pf(__expf(x));
}

// async global->LDS, 16B per lane; LDS dest = wave-uniform base + lane*16
__device__ __forceinline__ void gl2lds16(const _Float16* g, _Float16* l){
    __builtin_amdgcn_global_load_lds(
        (const __attribute__((address_space(1))) void*)g,
        (__attribute__((address_space(3))) void*)l, 16, 0, 0);
}

// Sum over each 16-lane DPP row via row_shr chain; result valid in lane 15
// of each row (lanes shifted past row start contribute 0; old=0 either way).
__device__ __forceinline__ float dpp_row_sum16(float x){
    float v = x;
    v += __int_as_float(__builtin_amdgcn_update_dpp(0, __float_as_int(v), 0x111, 0xf, 0xf, true));
    v += __int_as_float(__builtin_amdgcn_update_dpp(0, __float_as_int(v), 0x112, 0xf, 0xf, true));
    v += __int_as_float(__builtin_amdgcn_update_dpp(0, __float_as_int(v), 0x114, 0xf, 0xf, true));
    v += __int_as_float(__builtin_amdgcn_update_dpp(0, __float_as_int(v), 0x118, 0xf, 0xf, true));
    return v;
}

// ---------------------------------------------------------------------------
// fp32 -> fp16 convert of the three weight tensors, one dispatch
// ---------------------------------------------------------------------------
__global__ __launch_bounds__(256) void k_f2h3(const float* __restrict__ a0,
                                              const float* __restrict__ a1,
                                              const float* __restrict__ a2,
                                              _Float16* __restrict__ o0,
                                              _Float16* __restrict__ o1,
                                              _Float16* __restrict__ o2,
                                              int n0, int n1, int n2){
    int total = n0 + n1 + n2;
    for (int i = blockIdx.x * 256 + threadIdx.x; i < total; i += gridDim.x * 256){
        if (i < n0)            o0[i] = (_Float16)a0[i];
        else if (i < n0 + n1)  o1[i - n0] = (_Float16)a1[i - n0];
        else                   o2[i - n0 - n1] = (_Float16)a2[i - n0 - n1];
    }
}

// ---------------------------------------------------------------------------
// im2col for the conv projection: xcol[(b,l)][(ci,k)] = x[b,ci,l-1+k], fp16.
// ---------------------------------------------------------------------------
__global__ __launch_bounds__(256) void k_im2col(const float* __restrict__ x,
                                                _Float16* __restrict__ xcol){
    __shared__ float xs[CIN][68];      // 67 used
    int blk = blockIdx.x;              // 0..127
    int b  = blk >> 5;
    int l0 = (blk & 31) << 6;          // *64
    const float* xb = x + (size_t)b * CIN * LEN;
    for (int idx = threadIdx.x; idx < CIN * 67; idx += 256){
        int ci = idx / 67, j = idx % 67;
        int gl = l0 - 1 + j;
        xs[ci][j] = (gl >= 0 && gl < LEN) ? xb[ci * LEN + gl] : 0.f;
    }
    __syncthreads();
    #pragma unroll
    for (int v = 0; v < 16; v++){
        int id = v * 256 + threadIdx.x;   // 0..4095
        int rl = id >> 6, c = id & 63;    // row-in-tile, 16B chunk
        f16x8 pk;
        #pragma unroll
        for (int e = 0; e < 8; e++){
            int ci = c * 2 + (e >> 2), k = e & 3;
            pk[e] = (_Float16)xs[ci][rl + k];
        }
        *(f16x8*)&xcol[((size_t)(b * LEN + l0 + rl)) * 512 + c * 8] = pk;
    }
}

// ---------------------------------------------------------------------------
// Shared MFMA GEMM: C[M][N] = A[M][K] . Bw[N][K]^T, f16 inputs, fp32 acc.
// 128x128 tile, BK=32, 4 waves (2x2), each wave 4x4 mfma_f32_16x16x32_f16.
// EPI 0: u_h fp16; EPI 1: split z/xbc/dt(+softplus); EPI 2: fp32 (B,D,L).
// ---------------------------------------------------------------------------
template<int K, int EPI>
__global__ __launch_bounds__(256) void k_gemm(const _Float16* __restrict__ A,
                                              const _Float16* __restrict__ Bw,
                                              const float* __restrict__ dt_bias,
                                              _Float16* __restrict__ o_u,
                                              _Float16* __restrict__ o_z,
                                              _Float16* __restrict__ o_xbc,
                                              _Float16* __restrict__ o_dt,
                                              float* __restrict__ o_f){
    __shared__ __align__(16) _Float16 As[128 * 32];
    __shared__ __align__(16) _Float16 Bs[128 * 32];
    int tid  = threadIdx.x;
    int wv   = tid >> 6;
    int lane = tid & 63;
    int quad = lane >> 4;
    int l16  = lane & 15;
    int m0 = blockIdx.x * 128;
    int n0 = blockIdx.y * 128;
    int wm = (wv >> 1) * 64;
    int wn = (wv & 1) * 64;
    int srow = lane >> 2;              // 0..15 staging row
    int scol = (lane & 3) * 8;         // halves offset 0,8,16,24

    f32x4 acc[4][4];
    #pragma unroll
    for (int i = 0; i < 4; i++)
        #pragma unroll
        for (int j = 0; j < 4; j++)
            acc[i][j] = (f32x4){0.f, 0.f, 0.f, 0.f};

    for (int k0 = 0; k0 < K; k0 += 32){
        #pragma unroll
        for (int j = 0; j < 2; j++){
            int ar = m0 + wv * 32 + j * 16 + srow;
            gl2lds16(A + (size_t)ar * K + k0 + scol,
                     &As[(wv * 32 + j * 16) * 32]);
            int nr = n0 + wv * 32 + j * 16 + srow;
            if (EPI == 1) nr = nr > (DINPROJ - 1) ? (DINPROJ - 1) : nr;
            gl2lds16(Bw + (size_t)nr * K + k0 + scol,
                     &Bs[(wv * 32 + j * 16) * 32]);
        }
        __syncthreads();
        f16x8 af[4], bf[4];
        #pragma unroll
        for (int i = 0; i < 4; i++)
            af[i] = *(const f16x8*)&As[(wm + i * 16 + l16) * 32 + quad * 8];
        #pragma unroll
        for (int j = 0; j < 4; j++)
            bf[j] = *(const f16x8*)&Bs[(wn + j * 16 + l16) * 32 + quad * 8];
        #pragma unroll
        for (int i = 0; i < 4; i++)
            #pragma unroll
            for (int j = 0; j < 4; j++)
                acc[i][j] = __builtin_amdgcn_mfma_f32_16x16x32_f16(
                                af[i], bf[j], acc[i][j], 0, 0, 0);
        __syncthreads();
    }

    if (EPI == 0){
        #pragma unroll
        for (int j = 0; j < 4; j++){
            int col = n0 + wn + j * 16 + l16;
            #pragma unroll
            for (int i = 0; i < 4; i++){
                int row = m0 + wm + i * 16 + quad * 4;
                #pragma unroll
                for (int r = 0; r < 4; r++)
                    o_u[(size_t)(row + r) * DMODEL + col] = (_Float16)acc[i][j][r];
            }
        }
    } else if (EPI == 1){
        #pragma unroll
        for (int j = 0; j < 4; j++){
            int col = n0 + wn + j * 16 + l16;
            if (col < DINNER){
                #pragma unroll
                for (int i = 0; i < 4; i++){
                    int row = m0 + wm + i * 16 + quad * 4;
                    #pragma unroll
                    for (int r = 0; r < 4; r++)
                        o_z[(size_t)(row + r) * DINNER + col] = (_Float16)acc[i][j][r];
                }
            } else if (col < DINNER + CONVDIM){
                int cc = col - DINNER;
                #pragma unroll
                for (int i = 0; i < 4; i++){
                    int row = m0 + wm + i * 16 + quad * 4;
                    #pragma unroll
                    for (int r = 0; r < 4; r++)
                        o_xbc[(size_t)(row + r) * CONVDIM + cc] = (_Float16)acc[i][j][r];
                }
            } else if (col < DINPROJ){
                int hh = col - (DINNER + CONVDIM);
                float bias = dt_bias[hh];
                #pragma unroll
                for (int i = 0; i < 4; i++){
                    int row = m0 + wm + i * 16 + quad * 4;
                    #pragma unroll
                    for (int r = 0; r < 4; r++)
                        o_dt[(size_t)(row + r) * NHEADS + hh] =
                            (_Float16)softplus_(acc[i][j][r] + bias);
                }
            }
        }
    } else {
        #pragma unroll
        for (int i = 0; i < 4; i++){
            int row = m0 + wm + i * 16 + quad * 4;
            int b = row >> 11, l = row & (LEN - 1);
            #pragma unroll
            for (int j = 0; j < 4; j++){
                int d = n0 + wn + j * 16 + l16;
                *(f32x4*)&o_f[(((size_t)(b * DMODEL + d)) << 11) + l] = acc[i][j];
            }
        }
    }
}

// ---------------------------------------------------------------------------
// depthwise causal conv (4-tap) + bias + SiLU, fp16 in/out.
// ---------------------------------------------------------------------------
__global__ __launch_bounds__(256) void k_dwconv(const __half* __restrict__ xbc,
                                                const float* __restrict__ cw,
                                                const float* __restrict__ cb,
                                                __half* __restrict__ xcc){
    int idx = blockIdx.x * 256 + threadIdx.x;   // < 8192*800
    int c = idx % CONVDIM;
    int r = idx / CONVDIM;
    int l = r & (LEN - 1);
    float4 wv = *(const float4*)(cw + c * 4);
    float acc = cb[c];
    if (l >= 3){
        const __half* base = xbc + (size_t)(r - 3) * CONVDIM + c;
        acc += __half2float(base[0]) * wv.x + __half2float(base[CONVDIM]) * wv.y +
               __half2float(base[2 * CONVDIM]) * wv.z + __half2float(base[3 * CONVDIM]) * wv.w;
    } else {
        const float wk[4] = {wv.x, wv.y, wv.z, wv.w};
        for (int k = 0; k < 4; k++){
            int t = l - 3 + k;
            if (t >= 0) acc += __half2float(xbc[(size_t)(r + k - 3) * CONVDIM + c]) * wk[k];
        }
    }
    xcc[idx] = __float2half(silu_(acc));
}

// ---------------------------------------------------------------------------
// k_scanAC v2: block = (b, chunk, group of 16 heads); 256 thr = 4 waves,
// wave handles 4 heads (lanes: hl=lane>>4 head, n=lane&15 state index).
// All operands staged to LDS with coalesced 16B loads; n-reduction via DPP
// row_shr chain (VALU, no DS traffic). Emits y_local (+D_skip*x), chunk-final
// local state, and chunk decay; y corrected later by k_fixup (linearity).
// ---------------------------------------------------------------------------
__global__ __launch_bounds__(256) void k_scanAC(const __half* __restrict__ dtb,
                                                const __half* __restrict__ xcc,
                                                const float* __restrict__ A_log,
                                                const float* __restrict__ D_skip,
                                                __half* __restrict__ y,
                                                __half* __restrict__ cstate,
                                                float* __restrict__ dsum){
    __shared__ __align__(16) _Float16 xs_x[64][48];   // [t][j*3+p], 16 heads, 6KB
    __shared__ __align__(16) _Float16 xs_bc[64][32];  // [t][n]=B, [t][16+n]=C, 4KB
    __shared__ __align__(16) _Float16 xs_dt[64][16];  // [t][j], 2KB
    int blk = blockIdx.x;              // 0..2047
    int hg = blk & 15;
    int c  = (blk >> 4) & 31;
    int b  = blk >> 9;
    int tid = threadIdx.x;
    size_t row0 = (size_t)b * LEN + c * CHUNK;

    // staging: 768 16B segments, 3 per thread
    const _Float16* xc16 = (const _Float16*)xcc;
    const _Float16* dt16 = (const _Float16*)dtb;
    #pragma unroll
    for (int k = 0; k < 3; k++){
        int seg = tid + k * 256;
        if (seg < 384){
            int t = seg / 6, k16 = seg % 6;
            *(f16x8*)&xs_x[t][k16 * 8] =
                *(const f16x8*)(xc16 + (row0 + t) * CONVDIM + hg * 48 + k16 * 8);
        } else if (seg < 640){
            int i = seg - 384; int t = i >> 2, k4 = i & 3;
            *(f16x8*)&xs_bc[t][k4 * 8] =
                *(const f16x8*)(xc16 + (row0 + t) * CONVDIM + DINNER + k4 * 8);
        } else {
            int i = seg - 640; int t = i >> 1, k2 = i & 1;
            *(f16x8*)&xs_dt[t][k2 * 8] =
                *(const f16x8*)(dt16 + (row0 + t) * NHEADS + hg * 16 + k2 * 8);
        }
    }
    __syncthreads();

    int w    = tid >> 6;
    int lane = tid & 63;
    int hl   = lane >> 4;
    int n    = lane & 15;
    int jj   = w * 4 + hl;             // block-local head 0..15
    int h    = hg * 16 + jj;           // global head
    int c0   = h * 3;
    float A   = -__expf(A_log[h]);
    float Dsk = D_skip[h];

    float h0 = 0.f, h1 = 0.f, h2 = 0.f, sdt = 0.f;
    __half* yp = y + row0 * DINNER + c0;
    // software-pipelined LDS reads
    float vx0 = (float)xs_x[0][jj * 3 + 0];
    float vx1 = (float)xs_x[0][jj * 3 + 1];
    float vx2 = (float)xs_x[0][jj * 3 + 2];
    float vB  = (float)xs_bc[0][n];
    float vC  = (float)xs_bc[0][16 + n];
    float cdt = (float)xs_dt[0][jj];
    for (int t = 0; t < CHUNK; t++){
        int tn = (t + 1 < CHUNK) ? t + 1 : t;
        float nx0 = (float)xs_x[tn][jj * 3 + 0];
        float nx1 = (float)xs_x[tn][jj * 3 + 1];
        float nx2 = (float)xs_x[tn][jj * 3 + 2];
        float nB  = (float)xs_bc[tn][n];
        float nC  = (float)xs_bc[tn][16 + n];
        float ndt = (float)xs_dt[tn][jj];

        float dA  = __expf(cdt * A);
        float dtB = cdt * vB;
        h0 = fmaf(h0, dA, vx0 * dtB);
        h1 = fmaf(h1, dA, vx1 * dtB);
        h2 = fmaf(h2, dA, vx2 * dtB);
        sdt += cdt;
        float p0 = dpp_row_sum16(h0 * vC);
        float p1 = dpp_row_sum16(h1 * vC);
        float p2 = dpp_row_sum16(h2 * vC);
        if (n == 15){
            yp[0] = __float2half(fmaf(Dsk, vx0, p0));
            yp[1] = __float2half(fmaf(Dsk, vx1, p1));
            yp[2] = __float2half(fmaf(Dsk, vx2, p2));
        }
        yp += DINNER;
        vx0 = nx0; vx1 = nx1; vx2 = nx2; vB = nB; vC = nC; cdt = ndt;
    }
    size_t sbase = (((size_t)(b * NHEADS + h)) * NCHUNK + c) * 48;
    cstate[sbase + n]      = __float2half(h0);
    cstate[sbase + 16 + n] = __float2half(h1);
    cstate[sbase + 32 + n] = __float2half(h2);
    if (n == 0) dsum[(size_t)(b * NHEADS + h) * NCHUNK + c] = __expf(A * sdt);
}

// ---------------------------------------------------------------------------
// scan pass B: per (b,h), combine chunk summaries sequentially; overwrite
// cstate[c] in place with the INITIAL state of chunk c.
// ---------------------------------------------------------------------------
__global__ __launch_bounds__(64) void k_scanB(__half* __restrict__ cstate,
                                              const float* __restrict__ dsum){
    int bh = blockIdx.x;               // 0..1023
    int lane = threadIdx.x;
    if (lane >= 48) return;
    __half* st = cstate + (size_t)bh * NCHUNK * 48 + lane;
    const float* dd = dsum + (size_t)bh * NCHUNK;
    float H = 0.f;
    for (int c = 0; c < NCHUNK; c++){
        float d = dd[c];
        float s = __half2float(st[(size_t)c * 48]);
        st[(size_t)c * 48] = __float2half(H);
        H = fmaf(H, d, s);
    }
}

// ---------------------------------------------------------------------------
// k_fixup v2: exploits NGROUPS=1 (C shared by all heads).
// block = (b, chunk, t-half of 32 rows); 256 threads, thread = head.
// Phase 1: decay[t][h] = exp(A_h * cumsum(dt)) built with coalesced dt reads.
// Phase 2: y[t, h*3+p] += decay[t][h] * sum_n C[t,n]*Hinit[h,n,p];
//          y RMW is 6B/thread contiguous across threads (coalesced).
// ---------------------------------------------------------------------------
__global__ __launch_bounds__(256) void k_fixup(const __half* __restrict__ dtb,
                                               const __half* __restrict__ xcc,
                                               const float* __restrict__ A_log,
                                               const __half* __restrict__ cstate,
                                               __half* __restrict__ y){
    __shared__ __align__(16) _Float16 decay[32][256];  // 16KB
    __shared__ __align__(16) _Float16 Cs[32][16];      // 1KB
    int blk = blockIdx.x;              // 0..255
    int th = blk & 1;
    int c  = (blk >> 1) & 31;
    int b  = blk >> 6;
    int tid = threadIdx.x;             // = head
    int base_t = th * 32;
    size_t row0 = (size_t)b * LEN + c * CHUNK;

    // stage C rows for this half (32 rows x 32B)
    if (tid < 64){
        int i = tid >> 1, k = tid & 1;
        *(f16x8*)&Cs[i][k * 8] =
            *(const f16x8*)((const _Float16*)xcc +
                            (row0 + base_t + i) * CONVDIM + DINNER + DSTATE + k * 8);
    }
    // decay table: thread = head, sequential prefix over t
    {
        float A = -__expf(A_log[tid]);
        float cum = 0.f;
        const _Float16* dp = (const _Float16*)dtb + row0 * NHEADS + tid;
        for (int t = 0; t < CHUNK; t++){
            cum += (float)dp[(size_t)t * NHEADS];
            if (t >= base_t && t < base_t + 32)
                decay[t - base_t][tid] = (_Float16)__expf(A * cum);
        }
    }
    __syncthreads();

    // Hinit[3][16] for this thread's head
    const _Float16* hp = (const _Float16*)cstate +
                         (((size_t)(b * NHEADS + tid)) * NCHUNK + c) * 48;
    float Hi[3][16];
    #pragma unroll
    for (int p = 0; p < 3; p++){
        f16x8 a = *(const f16x8*)(hp + p * 16);
        f16x8 bq = *(const f16x8*)(hp + p * 16 + 8);
        #pragma unroll
        for (int e = 0; e < 8; e++){ Hi[p][e] = (float)a[e]; Hi[p][8 + e] = (float)bq[e]; }
    }
    __half* yb = y + (row0 + base_t) * DINNER + tid * 3;
    for (int i = 0; i < 32; i++){
        float s0 = 0.f, s1 = 0.f, s2 = 0.f;
        #pragma unroll
        for (int nn = 0; nn < 16; nn++){
            float cv = (float)Cs[i][nn];
            s0 = fmaf(cv, Hi[0][nn], s0);
            s1 = fmaf(cv, Hi[1][nn], s1);
            s2 = fmaf(cv, Hi[2][nn], s2);
        }
        float d = (float)decay[i][tid];
        __half* yp = yb + (size_t)i * DINNER;
        yp[0] = __float2half(__half2float(yp[0]) + d * s0);
        yp[1] = __float2half(__half2float(yp[1]) + d * s1);
        yp[2] = __float2half(__half2float(yp[2]) + d * s2);
    }
}

// ---------------------------------------------------------------------------
// gated RMSNorm (in place on y, fp16 storage, fp32 math)
// ---------------------------------------------------------------------------
__global__ __launch_bounds__(256) void k_norm(__half* __restrict__ y,
                                              const __half* __restrict__ z,
                                              const float* __restrict__ nw){
    __shared__ float wsum[4];
    size_t r = blockIdx.x;
    int tid = threadIdx.x;
    const __half* zr = z + r * DINNER;
    __half* yr = y + r * DINNER;
    int e0 = tid, e1 = tid + 256, e2 = tid + 512;
    float t0 = __half2float(yr[e0]) * silu_(__half2float(zr[e0]));
    float t1 = __half2float(yr[e1]) * silu_(__half2float(zr[e1]));
    float t2 = __half2float(yr[e2]) * silu_(__half2float(zr[e2]));
    float ss = t0 * t0 + t1 * t1 + t2 * t2;
    #pragma unroll
    for (int m = 1; m < 64; m <<= 1) ss += __shfl_xor(ss, m, 64);
    if ((tid & 63) == 0) wsum[tid >> 6] = ss;
    __syncthreads();
    float tot = wsum[0] + wsum[1] + wsum[2] + wsum[3];
    float sc = rsqrtf(tot / (float)DINNER + EPS_);
    yr[e0] = __float2half(t0 * sc * nw[e0]);
    yr[e1] = __float2half(t1 * sc * nw[e1]);
    yr[e2] = __float2half(t2 * sc * nw[e2]);
}

// ---------------------------------------------------------------------------
extern "C" void kernel_launch(void* const* d_in, const int* in_sizes, int n_in,
                              void* d_out, int out_size, void* d_ws, size_t ws_size,
                              hipStream_t stream) {
    const float* x          = (const float*)d_in[0];
    const float* proj_w     = (const float*)d_in[1];
    const float* in_proj_w  = (const float*)d_in[2];
    const float* conv_w     = (const float*)d_in[3];
    const float* conv_b     = (const float*)d_in[4];
    const float* dt_bias    = (const float*)d_in[5];
    const float* A_log      = (const float*)d_in[6];
    const float* D_skip     = (const float*)d_in[7];
    const float* norm_w     = (const float*)d_in[8];
    const float* out_proj_w = (const float*)d_in[9];
    float* out = (float*)d_out;

    // fp16 proj/in_proj weights live in d_out (dead until the final GEMM
    // overwrites all of d_out with the result).
    char* ob = (char*)d_out;
    _Float16* pw_h  = (_Float16*)ob;                   //   262,144 B (256x512)
    _Float16* ipw_h = (_Float16*)(ob + 262144);        //   933,888 B (1824x256)

    // Workspace (bytes), total 46,661,632 (~44.5 MiB, <= 48.9 MiB known-good):
    char* wsb = (char*)d_ws;
    _Float16* xcol  = (_Float16*)(wsb);                // 8192x512 fp16
    _Float16* u_h   = (_Float16*)(wsb + 8388608);      // 8192x256 fp16
    __half*   xcc_h = (__half*)(wsb);                  // 8192x800 fp16 (alias)
    __half*   z_h   = (__half*)(wsb + 13107200);       // 8192x768
    __half*   xbc_h = (__half*)(wsb + 25690112);       // 8192x800
    __half*   y_h   = xbc_h;                           // alias: xbc dead after dwconv
    __half*   dt_h  = (__half*)(wsb + 38797312);       // 8192x256
    __half*   cstate= (__half*)(wsb + 42991616);       // B*NH*NCHUNK*48
    float*    dsum  = (float*)(wsb + 46137344);        // B*NH*NCHUNK
    _Float16* opw_h = (_Float16*)(wsb + 46268416);     // 256x768 fp16

    k_f2h3  <<<96, 256, 0, stream>>>(proj_w, in_proj_w, out_proj_w,
                                     pw_h, ipw_h, opw_h,
                                     DMODEL * CIN * 4, DINPROJ * DMODEL,
                                     DMODEL * DINNER);
    k_im2col<<<128, 256, 0, stream>>>(x, xcol);
    k_gemm<512, 0><<<dim3(64, 2), 256, 0, stream>>>(xcol, pw_h, nullptr,
        u_h, nullptr, nullptr, nullptr, nullptr);
    k_gemm<256, 1><<<dim3(64, 15), 256, 0, stream>>>(u_h, ipw_h, dt_bias,
        nullptr, (_Float16*)z_h, (_Float16*)xbc_h, (_Float16*)dt_h, nullptr);
    k_dwconv<<<25600, 256, 0, stream>>>(xbc_h, conv_w, conv_b, xcc_h);
    k_scanAC<<<2048, 256, 0, stream>>>(dt_h, xcc_h, A_log, D_skip, y_h, cstate, dsum);
    k_scanB <<<1024, 64, 0, stream>>>(cstate, dsum);
    k_fixup <<<256, 256, 0, stream>>>(dt_h, xcc_h, A_log, cstate, y_h);
    k_norm  <<<8192, 256, 0, stream>>>(y_h, z_h, norm_w);
    k_gemm<768, 2><<<dim3(64, 2), 256, 0, stream>>>((const _Float16*)y_h, opw_h,
        nullptr, nullptr, nullptr, nullptr, nullptr, out);
}

// Round 8
// 320.323 us; speedup vs baseline: 1.1462x; 1.1462x over previous
//
#include <hip/hip_runtime.h>
#include <hip/hip_fp16.h>
#include <math.h>

// Problem constants
#define B_     4
#define CIN    128
#define LEN    2048
#define DMODEL 256
#define DSTATE 16
#define NHEADS 256
#define DINNER 768
#define CONVDIM 800      // DINNER + 2*DSTATE
#define DINPROJ 1824     // 2*DINNER + 2*DSTATE + NHEADS
#define EPS_   1e-5f
#define CHUNK  64
#define NCHUNK 32        // LEN / CHUNK

typedef _Float16 f16x8 __attribute__((ext_vector_type(8)));
typedef float    f32x4 __attribute__((ext_vector_type(4)));

__device__ __forceinline__ float silu_(float x){ return x / (1.0f + __expf(-x)); }
__device__ __forceinline__ float softplus_(float x){
    return x > 0.f ? x + log1pf(__expf(-x)) : log1pf(__expf(x));
}

// async global->LDS, 16B per lane; LDS dest = wave-uniform base + lane*16
__device__ __forceinline__ void gl2lds16(const _Float16* g, _Float16* l){
    __builtin_amdgcn_global_load_lds(
        (const __attribute__((address_space(1))) void*)g,
        (__attribute__((address_space(3))) void*)l, 16, 0, 0);
}

// ---------------------------------------------------------------------------
// fp32 -> fp16 convert of the three weight tensors, one dispatch
// ---------------------------------------------------------------------------
__global__ __launch_bounds__(256) void k_f2h3(const float* __restrict__ a0,
                                              const float* __restrict__ a1,
                                              const float* __restrict__ a2,
                                              _Float16* __restrict__ o0,
                                              _Float16* __restrict__ o1,
                                              _Float16* __restrict__ o2,
                                              int n0, int n1, int n2){
    int total = n0 + n1 + n2;
    for (int i = blockIdx.x * 256 + threadIdx.x; i < total; i += gridDim.x * 256){
        if (i < n0)            o0[i] = (_Float16)a0[i];
        else if (i < n0 + n1)  o1[i - n0] = (_Float16)a1[i - n0];
        else                   o2[i - n0 - n1] = (_Float16)a2[i - n0 - n1];
    }
}

// ---------------------------------------------------------------------------
// im2col for the conv projection: xcol[(b,l)][(ci,k)] = x[b,ci,l-1+k], fp16.
// ---------------------------------------------------------------------------
__global__ __launch_bounds__(256) void k_im2col(const float* __restrict__ x,
                                                _Float16* __restrict__ xcol){
    __shared__ float xs[CIN][68];      // 67 used
    int blk = blockIdx.x;              // 0..127
    int b  = blk >> 5;
    int l0 = (blk & 31) << 6;          // *64
    const float* xb = x + (size_t)b * CIN * LEN;
    for (int idx = threadIdx.x; idx < CIN * 67; idx += 256){
        int ci = idx / 67, j = idx % 67;
        int gl = l0 - 1 + j;
        xs[ci][j] = (gl >= 0 && gl < LEN) ? xb[ci * LEN + gl] : 0.f;
    }
    __syncthreads();
    #pragma unroll
    for (int v = 0; v < 16; v++){
        int id = v * 256 + threadIdx.x;   // 0..4095
        int rl = id >> 6, c = id & 63;    // row-in-tile, 16B chunk
        f16x8 pk;
        #pragma unroll
        for (int e = 0; e < 8; e++){
            int ci = c * 2 + (e >> 2), k = e & 3;
            pk[e] = (_Float16)xs[ci][rl + k];
        }
        *(f16x8*)&xcol[((size_t)(b * LEN + l0 + rl)) * 512 + c * 8] = pk;
    }
}

// ---------------------------------------------------------------------------
// Shared MFMA GEMM: C[M][N] = A[M][K] . Bw[N][K]^T, f16 inputs, fp32 acc.
// 128x128 tile, BK=32, 4 waves (2x2), each wave 4x4 mfma_f32_16x16x32_f16.
// EPI 0: u_h fp16; EPI 1: split z/xbc/dt(+softplus); EPI 2: fp32 (B,D,L).
// ---------------------------------------------------------------------------
template<int K, int EPI>
__global__ __launch_bounds__(256) void k_gemm(const _Float16* __restrict__ A,
                                              const _Float16* __restrict__ Bw,
                                              const float* __restrict__ dt_bias,
                                              _Float16* __restrict__ o_u,
                                              _Float16* __restrict__ o_z,
                                              _Float16* __restrict__ o_xbc,
                                              _Float16* __restrict__ o_dt,
                                              float* __restrict__ o_f){
    __shared__ __align__(16) _Float16 As[128 * 32];
    __shared__ __align__(16) _Float16 Bs[128 * 32];
    int tid  = threadIdx.x;
    int wv   = tid >> 6;
    int lane = tid & 63;
    int quad = lane >> 4;
    int l16  = lane & 15;
    int m0 = blockIdx.x * 128;
    int n0 = blockIdx.y * 128;
    int wm = (wv >> 1) * 64;
    int wn = (wv & 1) * 64;
    int srow = lane >> 2;              // 0..15 staging row
    int scol = (lane & 3) * 8;         // halves offset 0,8,16,24

    f32x4 acc[4][4];
    #pragma unroll
    for (int i = 0; i < 4; i++)
        #pragma unroll
        for (int j = 0; j < 4; j++)
            acc[i][j] = (f32x4){0.f, 0.f, 0.f, 0.f};

    for (int k0 = 0; k0 < K; k0 += 32){
        #pragma unroll
        for (int j = 0; j < 2; j++){
            int ar = m0 + wv * 32 + j * 16 + srow;
            gl2lds16(A + (size_t)ar * K + k0 + scol,
                     &As[(wv * 32 + j * 16) * 32]);
            int nr = n0 + wv * 32 + j * 16 + srow;
            if (EPI == 1) nr = nr > (DINPROJ - 1) ? (DINPROJ - 1) : nr;
            gl2lds16(Bw + (size_t)nr * K + k0 + scol,
                     &Bs[(wv * 32 + j * 16) * 32]);
        }
        __syncthreads();
        f16x8 af[4], bf[4];
        #pragma unroll
        for (int i = 0; i < 4; i++)
            af[i] = *(const f16x8*)&As[(wm + i * 16 + l16) * 32 + quad * 8];
        #pragma unroll
        for (int j = 0; j < 4; j++)
            bf[j] = *(const f16x8*)&Bs[(wn + j * 16 + l16) * 32 + quad * 8];
        #pragma unroll
        for (int i = 0; i < 4; i++)
            #pragma unroll
            for (int j = 0; j < 4; j++)
                acc[i][j] = __builtin_amdgcn_mfma_f32_16x16x32_f16(
                                af[i], bf[j], acc[i][j], 0, 0, 0);
        __syncthreads();
    }

    if (EPI == 0){
        #pragma unroll
        for (int j = 0; j < 4; j++){
            int col = n0 + wn + j * 16 + l16;
            #pragma unroll
            for (int i = 0; i < 4; i++){
                int row = m0 + wm + i * 16 + quad * 4;
                #pragma unroll
                for (int r = 0; r < 4; r++)
                    o_u[(size_t)(row + r) * DMODEL + col] = (_Float16)acc[i][j][r];
            }
        }
    } else if (EPI == 1){
        #pragma unroll
        for (int j = 0; j < 4; j++){
            int col = n0 + wn + j * 16 + l16;
            if (col < DINNER){
                #pragma unroll
                for (int i = 0; i < 4; i++){
                    int row = m0 + wm + i * 16 + quad * 4;
                    #pragma unroll
                    for (int r = 0; r < 4; r++)
                        o_z[(size_t)(row + r) * DINNER + col] = (_Float16)acc[i][j][r];
                }
            } else if (col < DINNER + CONVDIM){
                int cc = col - DINNER;
                #pragma unroll
                for (int i = 0; i < 4; i++){
                    int row = m0 + wm + i * 16 + quad * 4;
                    #pragma unroll
                    for (int r = 0; r < 4; r++)
                        o_xbc[(size_t)(row + r) * CONVDIM + cc] = (_Float16)acc[i][j][r];
                }
            } else if (col < DINPROJ){
                int hh = col - (DINNER + CONVDIM);
                float bias = dt_bias[hh];
                #pragma unroll
                for (int i = 0; i < 4; i++){
                    int row = m0 + wm + i * 16 + quad * 4;
                    #pragma unroll
                    for (int r = 0; r < 4; r++)
                        o_dt[(size_t)(row + r) * NHEADS + hh] =
                            (_Float16)softplus_(acc[i][j][r] + bias);
                }
            }
        }
    } else {
        #pragma unroll
        for (int i = 0; i < 4; i++){
            int row = m0 + wm + i * 16 + quad * 4;
            int b = row >> 11, l = row & (LEN - 1);
            #pragma unroll
            for (int j = 0; j < 4; j++){
                int d = n0 + wn + j * 16 + l16;
                *(f32x4*)&o_f[(((size_t)(b * DMODEL + d)) << 11) + l] = acc[i][j];
            }
        }
    }
}

// ---------------------------------------------------------------------------
// depthwise causal conv (4-tap) + bias + SiLU, vectorized: one thread = 8
// contiguous channels (f16x8 loads/stores, no div/mod by 800).
// ---------------------------------------------------------------------------
__global__ __launch_bounds__(256) void k_dwconv(const __half* __restrict__ xbc,
                                                const float* __restrict__ cw,
                                                const float* __restrict__ cb,
                                                __half* __restrict__ xcc){
    int idx = blockIdx.x * 256 + threadIdx.x;   // < 8192*100
    int seg = idx % 100;
    int r   = idx / 100;
    int l   = r & (LEN - 1);
    int c8  = seg * 8;
    const _Float16* base = (const _Float16*)xbc + (size_t)r * CONVDIM + c8;
    f16x8 zv = {0, 0, 0, 0, 0, 0, 0, 0};
    f16x8 x3 = *(const f16x8*)base;                                  // t
    f16x8 x2 = (l >= 1) ? *(const f16x8*)(base - CONVDIM) : zv;      // t-1
    f16x8 x1 = (l >= 2) ? *(const f16x8*)(base - 2 * CONVDIM) : zv;  // t-2
    f16x8 x0 = (l >= 3) ? *(const f16x8*)(base - 3 * CONVDIM) : zv;  // t-3
    f16x8 o;
    #pragma unroll
    for (int e = 0; e < 8; e++){
        float4 wv = *(const float4*)(cw + (size_t)(c8 + e) * 4);
        float acc = cb[c8 + e]
                  + (float)x0[e] * wv.x + (float)x1[e] * wv.y
                  + (float)x2[e] * wv.z + (float)x3[e] * wv.w;
        o[e] = (_Float16)silu_(acc);
    }
    *(f16x8*)((_Float16*)xcc + (size_t)r * CONVDIM + c8) = o;
}

// ---------------------------------------------------------------------------
// k_scanAC v3: proven v1 body (global scattered loads + ds_swizzle shfl
// reduction), but 4 waves per 256-thread workgroup (wave = one (b,hg,c) task)
// to break the 16-workgroups/CU occupancy cap of 1-wave blocks.
// Emits y_local (+D_skip*x), chunk-final local state, chunk decay.
// ---------------------------------------------------------------------------
__global__ __launch_bounds__(256) void k_scanAC(const __half* __restrict__ dtb,
                                                const __half* __restrict__ xcc,
                                                const float* __restrict__ A_log,
                                                const float* __restrict__ D_skip,
                                                __half* __restrict__ y,
                                                __half* __restrict__ cstate,
                                                float* __restrict__ dsum){
    int wave = threadIdx.x >> 6;
    int task = blockIdx.x * 4 + wave;  // 0..8191
    int c  = task & (NCHUNK - 1);
    int hg = (task >> 5) & 63;
    int b  = task >> 11;
    int lane = threadIdx.x & 63;
    int hl = lane >> 4;
    int n  = lane & 15;
    int h  = hg * 4 + hl;
    int c0 = h * 3;
    float A   = -__expf(A_log[h]);
    float Dsk = D_skip[h];
    int t0 = c * CHUNK;
    const __half* xr  = xcc + ((size_t)b * LEN + t0) * CONVDIM;
    const __half* dtp = dtb + ((size_t)b * LEN + t0) * NHEADS + h;
    float h0 = 0.f, h1 = 0.f, h2 = 0.f, sdt = 0.f;
    __half* yp = y + ((size_t)b * LEN + t0) * DINNER + c0;
    for (int t = 0; t < CHUNK; t++){
        float vx0 = __half2float(xr[c0]);
        float vx1 = __half2float(xr[c0 + 1]);
        float vx2 = __half2float(xr[c0 + 2]);
        float vB  = __half2float(xr[DINNER + n]);
        float vC  = __half2float(xr[DINNER + DSTATE + n]);
        float cdt = __half2float(dtp[(size_t)t * NHEADS]);
        float dA  = __expf(cdt * A);
        float dtB = cdt * vB;
        h0 = fmaf(h0, dA, vx0 * dtB);
        h1 = fmaf(h1, dA, vx1 * dtB);
        h2 = fmaf(h2, dA, vx2 * dtB);
        sdt += cdt;
        float p0 = h0 * vC, p1 = h1 * vC, p2 = h2 * vC;
        #pragma unroll
        for (int m = 1; m < 16; m <<= 1){
            p0 += __shfl_xor(p0, m, 64);
            p1 += __shfl_xor(p1, m, 64);
            p2 += __shfl_xor(p2, m, 64);
        }
        if (n < 3){
            float pv = (n == 0) ? p0 : ((n == 1) ? p1 : p2);
            float xv = (n == 0) ? vx0 : ((n == 1) ? vx1 : vx2);
            yp[n] = __float2half(fmaf(Dsk, xv, pv));
        }
        xr += CONVDIM;
        yp += DINNER;
    }
    size_t sbase = (((size_t)(b * NHEADS + h)) * NCHUNK + c) * 48;
    cstate[sbase + n]      = __float2half(h0);
    cstate[sbase + 16 + n] = __float2half(h1);
    cstate[sbase + 32 + n] = __float2half(h2);
    if (n == 0) dsum[(size_t)(b * NHEADS + h) * NCHUNK + c] = __expf(A * sdt);
}

// ---------------------------------------------------------------------------
// scan pass B: per (b,h), combine chunk summaries sequentially; overwrite
// cstate[c] in place with the INITIAL state of chunk c.
// ---------------------------------------------------------------------------
__global__ __launch_bounds__(64) void k_scanB(__half* __restrict__ cstate,
                                              const float* __restrict__ dsum){
    int bh = blockIdx.x;               // 0..1023
    int lane = threadIdx.x;
    if (lane >= 48) return;
    __half* st = cstate + (size_t)bh * NCHUNK * 48 + lane;
    const float* dd = dsum + (size_t)bh * NCHUNK;
    float H = 0.f;
    for (int c = 0; c < NCHUNK; c++){
        float d = dd[c];
        float s = __half2float(st[(size_t)c * 48]);
        st[(size_t)c * 48] = __float2half(H);
        H = fmaf(H, d, s);
    }
}

// ---------------------------------------------------------------------------
// k_fixup v2: exploits NGROUPS=1 (C shared by all heads).
// block = (b, chunk, t-half of 32 rows); 256 threads, thread = head.
// ---------------------------------------------------------------------------
__global__ __launch_bounds__(256) void k_fixup(const __half* __restrict__ dtb,
                                               const __half* __restrict__ xcc,
                                               const float* __restrict__ A_log,
                                               const __half* __restrict__ cstate,
                                               __half* __restrict__ y){
    __shared__ __align__(16) _Float16 decay[32][256];  // 16KB
    __shared__ __align__(16) _Float16 Cs[32][16];      // 1KB
    int blk = blockIdx.x;              // 0..255
    int th = blk & 1;
    int c  = (blk >> 1) & 31;
    int b  = blk >> 6;
    int tid = threadIdx.x;             // = head
    int base_t = th * 32;
    size_t row0 = (size_t)b * LEN + c * CHUNK;

    if (tid < 64){
        int i = tid >> 1, k = tid & 1;
        *(f16x8*)&Cs[i][k * 8] =
            *(const f16x8*)((const _Float16*)xcc +
                            (row0 + base_t + i) * CONVDIM + DINNER + DSTATE + k * 8);
    }
    {
        float A = -__expf(A_log[tid]);
        float cum = 0.f;
        const _Float16* dp = (const _Float16*)dtb + row0 * NHEADS + tid;
        for (int t = 0; t < CHUNK; t++){
            cum += (float)dp[(size_t)t * NHEADS];
            if (t >= base_t && t < base_t + 32)
                decay[t - base_t][tid] = (_Float16)__expf(A * cum);
        }
    }
    __syncthreads();

    const _Float16* hp = (const _Float16*)cstate +
                         (((size_t)(b * NHEADS + tid)) * NCHUNK + c) * 48;
    float Hi[3][16];
    #pragma unroll
    for (int p = 0; p < 3; p++){
        f16x8 a = *(const f16x8*)(hp + p * 16);
        f16x8 bq = *(const f16x8*)(hp + p * 16 + 8);
        #pragma unroll
        for (int e = 0; e < 8; e++){ Hi[p][e] = (float)a[e]; Hi[p][8 + e] = (float)bq[e]; }
    }
    __half* yb = y + (row0 + base_t) * DINNER + tid * 3;
    for (int i = 0; i < 32; i++){
        float s0 = 0.f, s1 = 0.f, s2 = 0.f;
        #pragma unroll
        for (int nn = 0; nn < 16; nn++){
            float cv = (float)Cs[i][nn];
            s0 = fmaf(cv, Hi[0][nn], s0);
            s1 = fmaf(cv, Hi[1][nn], s1);
            s2 = fmaf(cv, Hi[2][nn], s2);
        }
        float d = (float)decay[i][tid];
        __half* yp = yb + (size_t)i * DINNER;
        yp[0] = __float2half(__half2float(yp[0]) + d * s0);
        yp[1] = __float2half(__half2float(yp[1]) + d * s1);
        yp[2] = __float2half(__half2float(yp[2]) + d * s2);
    }
}

// ---------------------------------------------------------------------------
// gated RMSNorm (in place on y, fp16 storage, fp32 math)
// ---------------------------------------------------------------------------
__global__ __launch_bounds__(256) void k_norm(__half* __restrict__ y,
                                              const __half* __restrict__ z,
                                              const float* __restrict__ nw){
    __shared__ float wsum[4];
    size_t r = blockIdx.x;
    int tid = threadIdx.x;
    const __half* zr = z + r * DINNER;
    __half* yr = y + r * DINNER;
    int e0 = tid, e1 = tid + 256, e2 = tid + 512;
    float t0 = __half2float(yr[e0]) * silu_(__half2float(zr[e0]));
    float t1 = __half2float(yr[e1]) * silu_(__half2float(zr[e1]));
    float t2 = __half2float(yr[e2]) * silu_(__half2float(zr[e2]));
    float ss = t0 * t0 + t1 * t1 + t2 * t2;
    #pragma unroll
    for (int m = 1; m < 64; m <<= 1) ss += __shfl_xor(ss, m, 64);
    if ((tid & 63) == 0) wsum[tid >> 6] = ss;
    __syncthreads();
    float tot = wsum[0] + wsum[1] + wsum[2] + wsum[3];
    float sc = rsqrtf(tot / (float)DINNER + EPS_);
    yr[e0] = __float2half(t0 * sc * nw[e0]);
    yr[e1] = __float2half(t1 * sc * nw[e1]);
    yr[e2] = __float2half(t2 * sc * nw[e2]);
}

// ---------------------------------------------------------------------------
extern "C" void kernel_launch(void* const* d_in, const int* in_sizes, int n_in,
                              void* d_out, int out_size, void* d_ws, size_t ws_size,
                              hipStream_t stream) {
    const float* x          = (const float*)d_in[0];
    const float* proj_w     = (const float*)d_in[1];
    const float* in_proj_w  = (const float*)d_in[2];
    const float* conv_w     = (const float*)d_in[3];
    const float* conv_b     = (const float*)d_in[4];
    const float* dt_bias    = (const float*)d_in[5];
    const float* A_log      = (const float*)d_in[6];
    const float* D_skip     = (const float*)d_in[7];
    const float* norm_w     = (const float*)d_in[8];
    const float* out_proj_w = (const float*)d_in[9];
    float* out = (float*)d_out;

    // fp16 proj/in_proj weights live in d_out (dead until the final GEMM
    // overwrites all of d_out with the result).
    char* ob = (char*)d_out;
    _Float16* pw_h  = (_Float16*)ob;                   //   262,144 B (256x512)
    _Float16* ipw_h = (_Float16*)(ob + 262144);        //   933,888 B (1824x256)

    // Workspace (bytes), total 46,661,632 (~44.5 MiB, <= 48.9 MiB known-good):
    char* wsb = (char*)d_ws;
    _Float16* xcol  = (_Float16*)(wsb);                // 8192x512 fp16
    _Float16* u_h   = (_Float16*)(wsb + 8388608);      // 8192x256 fp16
    __half*   xcc_h = (__half*)(wsb);                  // 8192x800 fp16 (alias)
    __half*   z_h   = (__half*)(wsb + 13107200);       // 8192x768
    __half*   xbc_h = (__half*)(wsb + 25690112);       // 8192x800
    __half*   y_h   = xbc_h;                           // alias: xbc dead after dwconv
    __half*   dt_h  = (__half*)(wsb + 38797312);       // 8192x256
    __half*   cstate= (__half*)(wsb + 42991616);       // B*NH*NCHUNK*48
    float*    dsum  = (float*)(wsb + 46137344);        // B*NH*NCHUNK
    _Float16* opw_h = (_Float16*)(wsb + 46268416);     // 256x768 fp16

    k_f2h3  <<<96, 256, 0, stream>>>(proj_w, in_proj_w, out_proj_w,
                                     pw_h, ipw_h, opw_h,
                                     DMODEL * CIN * 4, DINPROJ * DMODEL,
                                     DMODEL * DINNER);
    k_im2col<<<128, 256, 0, stream>>>(x, xcol);
    k_gemm<512, 0><<<dim3(64, 2), 256, 0, stream>>>(xcol, pw_h, nullptr,
        u_h, nullptr, nullptr, nullptr, nullptr);
    k_gemm<256, 1><<<dim3(64, 15), 256, 0, stream>>>(u_h, ipw_h, dt_bias,
        nullptr, (_Float16*)z_h, (_Float16*)xbc_h, (_Float16*)dt_h, nullptr);
    k_dwconv<<<3200, 256, 0, stream>>>(xbc_h, conv_w, conv_b, xcc_h);
    k_scanAC<<<2048, 256, 0, stream>>>(dt_h, xcc_h, A_log, D_skip, y_h, cstate, dsum);
    k_scanB <<<1024, 64, 0, stream>>>(cstate, dsum);
    k_fixup <<<256, 256, 0, stream>>>(dt_h, xcc_h, A_log, cstate, y_h);
    k_norm  <<<8192, 256, 0, stream>>>(y_h, z_h, norm_w);
    k_gemm<768, 2><<<dim3(64, 2), 256, 0, stream>>>((const _Float16*)y_h, opw_h,
        nullptr, nullptr, nullptr, nullptr, nullptr, out);
}